// Round 3
// baseline (1348.967 us; speedup 1.0000x reference)
//
#include <hip/hip_runtime.h>

// Problem constants (fixed by reference)
#define NN 100000
#define EE 1600000
#define HH 128

// ---------------------------------------------------------------------------
// init: zero deg + cursor
// ---------------------------------------------------------------------------
__global__ __launch_bounds__(256) void zero_kernel(int* __restrict__ deg,
                                                   int* __restrict__ cursor) {
    int i = blockIdx.x * 256 + threadIdx.x;
    if (i < NN) { deg[i] = 0; cursor[i] = 0; }
}

// ---------------------------------------------------------------------------
// CSR build: count -> scan -> fill
// ---------------------------------------------------------------------------
__global__ __launch_bounds__(256) void count_kernel(const int* __restrict__ dst,
                                                    int* __restrict__ deg) {
    int e = blockIdx.x * 256 + threadIdx.x;
    if (e < EE) atomicAdd(&deg[dst[e]], 1);
}

// 391 blocks x 256: per-block scan + block totals
__global__ __launch_bounds__(256) void scan1_kernel(const int* __restrict__ deg,
                                                    int* __restrict__ offs,
                                                    int* __restrict__ bsums) {
    __shared__ int lds[256];
    int i = blockIdx.x * 256 + threadIdx.x;
    int v = (i < NN) ? deg[i] : 0;
    lds[threadIdx.x] = v;
    __syncthreads();
    for (int st = 1; st < 256; st <<= 1) {
        int t = (threadIdx.x >= st) ? lds[threadIdx.x - st] : 0;
        __syncthreads();
        lds[threadIdx.x] += t;
        __syncthreads();
    }
    if (i < NN) offs[i] = lds[threadIdx.x] - v;       // exclusive within block
    if (threadIdx.x == 255) bsums[blockIdx.x] = lds[255];
}

// single block of 512: exclusive scan of 391 block sums
__global__ __launch_bounds__(512) void scan2_kernel(int* __restrict__ bsums, int nb) {
    __shared__ int lds[512];
    int v = (threadIdx.x < nb) ? bsums[threadIdx.x] : 0;
    lds[threadIdx.x] = v;
    __syncthreads();
    for (int st = 1; st < 512; st <<= 1) {
        int t = (threadIdx.x >= st) ? lds[threadIdx.x - st] : 0;
        __syncthreads();
        lds[threadIdx.x] += t;
        __syncthreads();
    }
    if (threadIdx.x < nb) bsums[threadIdx.x] = lds[threadIdx.x] - v;
}

__global__ __launch_bounds__(256) void scan3_kernel(int* __restrict__ offs,
                                                    const int* __restrict__ bsums,
                                                    const int* __restrict__ deg,
                                                    float* __restrict__ inv) {
    int i = blockIdx.x * 256 + threadIdx.x;
    if (i < NN) {
        offs[i] += bsums[blockIdx.x];
        inv[i] = 1.0f / fmaxf((float)deg[i], 1.0f);
    }
    if (i == 0) offs[NN] = EE;   // every edge's dst is in [0,N) -> total == E
}

__global__ __launch_bounds__(256) void fill_kernel(const int* __restrict__ srcv,
                                                   const int* __restrict__ dstv,
                                                   const int* __restrict__ offs,
                                                   int* __restrict__ cursor,
                                                   int* __restrict__ csr) {
    int e = blockIdx.x * 256 + threadIdx.x;
    if (e < EE) {
        int d = dstv[e];
        int p = offs[d] + atomicAdd(&cursor[d], 1);
        csr[p] = srcv[e];
    }
}

// ---------------------------------------------------------------------------
// Dense projection: z = h @ Wl (written IN-PLACE over hin's rows),
//                   r = h @ Wr + b (to rout)
// block = 256 threads, tile = 32 rows x 128 cols. Each block reads only its
// own 32 rows into LDS, syncs, then overwrites them -> in-place is safe.
// ---------------------------------------------------------------------------
template <int K, bool FIRST>
__global__ __launch_bounds__(256) void gemm_kernel(
    const float* hin,                         // aliases zout when !FIRST
    const float* __restrict__ x0, const float* __restrict__ x1,
    const float* __restrict__ x2, const float* __restrict__ x3,
    const float* __restrict__ Wl, const float* __restrict__ Wr,
    const float* __restrict__ b,
    float* zout, float* __restrict__ rout) {
    constexpr int LDK = K + 4;                // pad: conflict-free, 16B-aligned rows
    __shared__ float lds[32 * LDK];
    const int tid = threadIdx.x;
    const int i0  = blockIdx.x * 32;

    for (int idx = tid; idx < 32 * (K / 4); idx += 256) {
        int row = idx / (K / 4), c4 = idx % (K / 4);
        int col = c4 * 4;
        float4 v;
        if (FIRST) {
            const float* s = (col < 64) ? x0 : (col < 128) ? x1
                           : (col < 192) ? x2 : x3;
            v = *(const float4*)&s[(size_t)(i0 + row) * 64 + (col & 63)];
        } else {
            v = *(const float4*)&hin[(size_t)(i0 + row) * K + col];
        }
        *(float4*)&lds[row * LDK + col] = v;
    }
    __syncthreads();

    const int j     = tid & 127;
    const int rbase = (tid >> 7) * 16;
    float accz[16], accr[16];
#pragma unroll
    for (int t = 0; t < 16; ++t) { accz[t] = 0.f; accr[t] = 0.f; }

    for (int k = 0; k < K; k += 4) {
        float wl[4], wr[4];
#pragma unroll
        for (int u = 0; u < 4; ++u) {
            wl[u] = Wl[(k + u) * HH + j];
            wr[u] = Wr[(k + u) * HH + j];
        }
#pragma unroll
        for (int t = 0; t < 16; ++t) {
            const float4 hv = *(const float4*)&lds[(rbase + t) * LDK + k];
            accz[t] += hv.x * wl[0] + hv.y * wl[1] + hv.z * wl[2] + hv.w * wl[3];
            accr[t] += hv.x * wr[0] + hv.y * wr[1] + hv.z * wr[2] + hv.w * wr[3];
        }
    }

    const float bj = b[j];
#pragma unroll
    for (int t = 0; t < 16; ++t) {
        const size_t row = (size_t)(i0 + rbase + t);
        zout[row * HH + j] = accz[t];
        rout[row * HH + j] = accr[t] + bj;
    }
}

// ---------------------------------------------------------------------------
// Aggregation + combine: h_out = relu(mean_{in-edges}(z[src]) + r)
// one wave per node, 2 features/lane. Reads r from rio[i], writes h back over
// rio[i] (own row only -> no cross-block hazard). z is a different buffer.
// ---------------------------------------------------------------------------
__global__ __launch_bounds__(256) void aggregate_kernel(
    const float* __restrict__ z, float* __restrict__ rio,
    const int* __restrict__ offs, const int* __restrict__ csr,
    const float* __restrict__ inv) {
    const int i    = (blockIdx.x * 256 + threadIdx.x) >> 6;
    const int lane = threadIdx.x & 63;
    if (i >= NN) return;
    const int beg = offs[i], end = offs[i + 1];
    float ax = 0.f, ay = 0.f;
    for (int e = beg; e < end; ++e) {
        const int s = csr[e];
        const float2 zv = *(const float2*)&z[(size_t)s * HH + lane * 2];
        ax += zv.x;
        ay += zv.y;
    }
    const float iv = inv[i];
    const float2 rv = *(const float2*)&rio[(size_t)i * HH + lane * 2];
    float2 o;
    o.x = fmaxf(ax * iv + rv.x, 0.f);
    o.y = fmaxf(ay * iv + rv.y, 0.f);
    *(float2*)&rio[(size_t)i * HH + lane * 2] = o;
}

// ---------------------------------------------------------------------------
// Layer 3: z3 = h @ Wl3, r3 = h @ Wr3 + b3 (one wave per node, dot-128)
// ---------------------------------------------------------------------------
__global__ __launch_bounds__(256) void proj3_kernel(
    const float* __restrict__ h, const float* __restrict__ Wl,
    const float* __restrict__ Wr, const float* __restrict__ b,
    float* __restrict__ z3, float* __restrict__ r3) {
    const int i    = (blockIdx.x * 256 + threadIdx.x) >> 6;
    const int lane = threadIdx.x & 63;
    if (i >= NN) return;
    const float2 hv  = *(const float2*)&h[(size_t)i * HH + lane * 2];
    const float2 wl2 = *(const float2*)&Wl[lane * 2];
    const float2 wr2 = *(const float2*)&Wr[lane * 2];
    float al = hv.x * wl2.x + hv.y * wl2.y;
    float ar = hv.x * wr2.x + hv.y * wr2.y;
#pragma unroll
    for (int m = 32; m; m >>= 1) {
        al += __shfl_xor(al, m, 64);
        ar += __shfl_xor(ar, m, 64);
    }
    if (lane == 0) {
        z3[i] = al;
        r3[i] = ar + b[0];
    }
}

// Final: out[i] = sigmoid(mean(z3[src]) + r3[i]); per-block partial sums
__global__ __launch_bounds__(256) void final_kernel(
    const float* __restrict__ z3, const float* __restrict__ r3,
    const int* __restrict__ offs, const int* __restrict__ csr,
    const float* __restrict__ inv, float* __restrict__ out,
    float* __restrict__ partial) {
    __shared__ float red[4];
    const int i    = (blockIdx.x * 256 + threadIdx.x) >> 6;
    const int lane = threadIdx.x & 63;
    const int w    = threadIdx.x >> 6;
    float v = 0.f;
    if (i < NN) {
        const int beg = offs[i], end = offs[i + 1];
        float a = 0.f;
        for (int e = beg + lane; e < end; e += 64) a += z3[csr[e]];
#pragma unroll
        for (int m = 32; m; m >>= 1) a += __shfl_xor(a, m, 64);
        const float pre = a * inv[i] + r3[i];
        const float s = 1.f / (1.f + __expf(-pre));
        if (lane == 0) { out[i] = s; v = s; }
    }
    if (lane == 0) red[w] = v;
    __syncthreads();
    if (threadIdx.x == 0)
        partial[blockIdx.x] = red[0] + red[1] + red[2] + red[3];
}

__global__ __launch_bounds__(256) void mean_kernel(const float* __restrict__ partial,
                                                   int nb, float* __restrict__ out) {
    __shared__ float lds[256];
    float s = 0.f;
    for (int i = threadIdx.x; i < nb; i += 256) s += partial[i];
    lds[threadIdx.x] = s;
    __syncthreads();
    for (int st = 128; st; st >>= 1) {
        if (threadIdx.x < st) lds[threadIdx.x] += lds[threadIdx.x + st];
        __syncthreads();
    }
    if (threadIdx.x == 0) out[NN] = lds[0] / (float)NN;
}

// ---------------------------------------------------------------------------
extern "C" void kernel_launch(void* const* d_in, const int* in_sizes, int n_in,
                              void* d_out, int out_size, void* d_ws, size_t ws_size,
                              hipStream_t stream) {
    const float* x    = (const float*)d_in[0];
    const float* diff = (const float*)d_in[1];
    const float* rec  = (const float*)d_in[2];
    const float* hid  = (const float*)d_in[3];
    const int* edge   = (const int*)d_in[4];
    const int* esrc = edge;        // row 0
    const int* edst = edge + EE;   // row 1
    const float* Wl0 = (const float*)d_in[5];
    const float* Wr0 = (const float*)d_in[6];
    const float* b0  = (const float*)d_in[7];
    const float* Wl1 = (const float*)d_in[8];
    const float* Wr1 = (const float*)d_in[9];
    const float* b1  = (const float*)d_in[10];
    const float* Wl2 = (const float*)d_in[11];
    const float* Wr2 = (const float*)d_in[12];
    const float* b2  = (const float*)d_in[13];
    const float* Wl3 = (const float*)d_in[14];
    const float* Wr3 = (const float*)d_in[15];
    const float* b3  = (const float*)d_in[16];
    float* out = (float*)d_out;

    // workspace carve-out (256B aligned) — total ~112 MB
    char* w = (char*)d_ws;
    auto alloc = [&](size_t bytes) -> void* {
        void* p = (void*)w;
        w += (bytes + 255) & ~(size_t)255;
        return p;
    };
    float* bufA    = (float*)alloc((size_t)NN * HH * 4);   // 51.2 MB
    float* bufB    = (float*)alloc((size_t)NN * HH * 4);   // 51.2 MB
    int*   csr     = (int*)alloc((size_t)EE * 4);          // 6.4 MB
    int*   deg     = (int*)alloc((size_t)NN * 4);
    float* inv     = (float*)alloc((size_t)NN * 4);
    int*   offs    = (int*)alloc((size_t)(NN + 1) * 4);
    int*   cursor  = (int*)alloc((size_t)NN * 4);
    float* z3      = (float*)alloc((size_t)NN * 4);
    float* r3      = (float*)alloc((size_t)NN * 4);
    float* partial = (float*)alloc((size_t)25000 * 4);
    int*   bsums   = (int*)alloc((size_t)512 * 4);

    const int EB  = (EE + 255) / 256;   // 6250
    const int NB1 = (NN + 255) / 256;   // 391
    const int GG  = NN / 32;            // 3125 (N % 32 == 0)
    const int WB  = (NN + 3) / 4;       // 25000 (4 waves/block, 1 node/wave)

    zero_kernel<<<NB1, 256, 0, stream>>>(deg, cursor);
    count_kernel<<<EB, 256, 0, stream>>>(edst, deg);
    scan1_kernel<<<NB1, 256, 0, stream>>>(deg, offs, bsums);
    scan2_kernel<<<1, 512, 0, stream>>>(bsums, NB1);
    scan3_kernel<<<NB1, 256, 0, stream>>>(offs, bsums, deg, inv);
    fill_kernel<<<EB, 256, 0, stream>>>(esrc, edst, offs, cursor, csr);

    // L0: K=256 from 4 inputs; z -> A, r -> B; agg: h1 -> B (over r)
    gemm_kernel<256, true><<<GG, 256, 0, stream>>>(nullptr, x, diff, rec, hid,
                                                   Wl0, Wr0, b0, bufA, bufB);
    aggregate_kernel<<<WB, 256, 0, stream>>>(bufA, bufB, offs, csr, inv);

    // L1: h in B; z in-place -> B, r -> A; agg: h2 -> A
    gemm_kernel<128, false><<<GG, 256, 0, stream>>>(bufB, nullptr, nullptr, nullptr, nullptr,
                                                    Wl1, Wr1, b1, bufB, bufA);
    aggregate_kernel<<<WB, 256, 0, stream>>>(bufB, bufA, offs, csr, inv);

    // L2: h in A; z in-place -> A, r -> B; agg: h3 -> B
    gemm_kernel<128, false><<<GG, 256, 0, stream>>>(bufA, nullptr, nullptr, nullptr, nullptr,
                                                    Wl2, Wr2, b2, bufA, bufB);
    aggregate_kernel<<<WB, 256, 0, stream>>>(bufA, bufB, offs, csr, inv);

    // L3: project to scalar, aggregate scalars, sigmoid + mean
    proj3_kernel<<<WB, 256, 0, stream>>>(bufB, Wl3, Wr3, b3, z3, r3);
    final_kernel<<<WB, 256, 0, stream>>>(z3, r3, offs, csr, inv, out, partial);
    mean_kernel<<<1, 256, 0, stream>>>(partial, WB, out);
}

// Round 4
// 1020.179 us; speedup vs baseline: 1.3223x; 1.3223x over previous
//
#include <hip/hip_runtime.h>
#include <hip/hip_bf16.h>

// Problem constants (fixed by reference)
#define NN 100000
#define EE 1600000
#define HH 128

typedef short bf16x8 __attribute__((ext_vector_type(8)));
typedef float f32x4  __attribute__((ext_vector_type(4)));

// ---------------------------------------------------------------------------
// init: zero deg + cursor
// ---------------------------------------------------------------------------
__global__ __launch_bounds__(256) void zero_kernel(int* __restrict__ deg,
                                                   int* __restrict__ cursor) {
    int i = blockIdx.x * 256 + threadIdx.x;
    if (i < NN) { deg[i] = 0; cursor[i] = 0; }
}

// ---------------------------------------------------------------------------
// CSR build: count -> scan -> fill
// ---------------------------------------------------------------------------
__global__ __launch_bounds__(256) void count_kernel(const int* __restrict__ dst,
                                                    int* __restrict__ deg) {
    int e = blockIdx.x * 256 + threadIdx.x;
    if (e < EE) atomicAdd(&deg[dst[e]], 1);
}

__global__ __launch_bounds__(256) void scan1_kernel(const int* __restrict__ deg,
                                                    int* __restrict__ offs,
                                                    int* __restrict__ bsums) {
    __shared__ int lds[256];
    int i = blockIdx.x * 256 + threadIdx.x;
    int v = (i < NN) ? deg[i] : 0;
    lds[threadIdx.x] = v;
    __syncthreads();
    for (int st = 1; st < 256; st <<= 1) {
        int t = (threadIdx.x >= st) ? lds[threadIdx.x - st] : 0;
        __syncthreads();
        lds[threadIdx.x] += t;
        __syncthreads();
    }
    if (i < NN) offs[i] = lds[threadIdx.x] - v;       // exclusive within block
    if (threadIdx.x == 255) bsums[blockIdx.x] = lds[255];
}

__global__ __launch_bounds__(512) void scan2_kernel(int* __restrict__ bsums, int nb) {
    __shared__ int lds[512];
    int v = (threadIdx.x < nb) ? bsums[threadIdx.x] : 0;
    lds[threadIdx.x] = v;
    __syncthreads();
    for (int st = 1; st < 512; st <<= 1) {
        int t = (threadIdx.x >= st) ? lds[threadIdx.x - st] : 0;
        __syncthreads();
        lds[threadIdx.x] += t;
        __syncthreads();
    }
    if (threadIdx.x < nb) bsums[threadIdx.x] = lds[threadIdx.x] - v;
}

__global__ __launch_bounds__(256) void scan3_kernel(int* __restrict__ offs,
                                                    const int* __restrict__ bsums,
                                                    const int* __restrict__ deg,
                                                    float* __restrict__ inv) {
    int i = blockIdx.x * 256 + threadIdx.x;
    if (i < NN) {
        offs[i] += bsums[blockIdx.x];
        inv[i] = 1.0f / fmaxf((float)deg[i], 1.0f);
    }
    if (i == 0) offs[NN] = EE;
}

__global__ __launch_bounds__(256) void fill_kernel(const int* __restrict__ srcv,
                                                   const int* __restrict__ dstv,
                                                   const int* __restrict__ offs,
                                                   int* __restrict__ cursor,
                                                   int* __restrict__ csr) {
    int e = blockIdx.x * 256 + threadIdx.x;
    if (e < EE) {
        int d = dstv[e];
        int p = offs[d] + atomicAdd(&cursor[d], 1);
        csr[p] = srcv[e];
    }
}

// ---------------------------------------------------------------------------
// h0 convert: concat 4 f32 [N,64] inputs -> bf16 [N,256]
// one thread per 4 elements (never crosses a source boundary)
// ---------------------------------------------------------------------------
__global__ __launch_bounds__(256) void h0_kernel(
    const float* __restrict__ x0, const float* __restrict__ x1,
    const float* __restrict__ x2, const float* __restrict__ x3,
    __hip_bfloat16* __restrict__ h0) {
    int t = blockIdx.x * 256 + threadIdx.x;            // 0 .. N*64-1
    if (t >= NN * 64) return;
    int i = t >> 6;
    int c = (t & 63) * 4;                              // 0..252, step 4
    const float* s = (c < 64) ? x0 : (c < 128) ? x1 : (c < 192) ? x2 : x3;
    float4 v = *(const float4*)&s[(size_t)i * 64 + (c & 63)];
    __hip_bfloat162 p0, p1;
    p0.x = __float2bfloat16(v.x); p0.y = __float2bfloat16(v.y);
    p1.x = __float2bfloat16(v.z); p1.y = __float2bfloat16(v.w);
    *(__hip_bfloat162*)&h0[(size_t)i * 256 + c]     = p0;
    *(__hip_bfloat162*)&h0[(size_t)i * 256 + c + 2] = p1;
}

// ---------------------------------------------------------------------------
// Weight prep: WT[n][k] = (n<128 ? Wl[k][n] : Wr[k][n-128]) as bf16.
// Rows n of WT are contiguous in k -> B-fragment loads are 16B contiguous.
// ---------------------------------------------------------------------------
__global__ __launch_bounds__(256) void prepw_kernel(
    const float* __restrict__ Wl0, const float* __restrict__ Wr0,
    const float* __restrict__ Wl1, const float* __restrict__ Wr1,
    const float* __restrict__ Wl2, const float* __restrict__ Wr2,
    __hip_bfloat16* __restrict__ WT0, __hip_bfloat16* __restrict__ WT1,
    __hip_bfloat16* __restrict__ WT2) {
    int t = blockIdx.x * 256 + threadIdx.x;            // 0 .. 131071
    if (t < 65536) {                                   // layer 0: K=256
        int k = t & 255, n = t >> 8;
        float v = (n < 128) ? Wl0[(size_t)k * 128 + n] : Wr0[(size_t)k * 128 + (n - 128)];
        WT0[(size_t)n * 256 + k] = __float2bfloat16(v);
    } else {
        t -= 65536;
        int layer = t >> 15;                           // 0 -> L1, 1 -> L2
        int u = t & 32767;
        int k = u & 127, n = u >> 7;
        const float* Wl = layer ? Wl2 : Wl1;
        const float* Wr = layer ? Wr2 : Wr1;
        __hip_bfloat16* WT = layer ? WT2 : WT1;
        float v = (n < 128) ? Wl[(size_t)k * 128 + n] : Wr[(size_t)k * 128 + (n - 128)];
        WT[(size_t)n * 128 + k] = __float2bfloat16(v);
    }
}

// ---------------------------------------------------------------------------
// MFMA GEMM: [z | r] = h @ [Wl | Wr] (+b on r). bf16 in, f32 acc, bf16 out.
// Block = 256 threads = 4 waves; block tile = 64 rows x 256 cols; each wave
// owns 64 cols (waves 0,1 -> z; waves 2,3 -> r). No LDS. A,B fragments are
// 16B-contiguous global loads (A: lane&15=row, quad*8=k; B from WT rows).
// zout may alias hin: each block writes only rows it reads; __syncthreads()
// before the epilogue orders all A-loads before any store within the block.
// ---------------------------------------------------------------------------
template <int K>
__global__ __launch_bounds__(256) void gemm_kernel(
    const __hip_bfloat16* hin, const __hip_bfloat16* __restrict__ wt,
    const float* __restrict__ bias,
    __hip_bfloat16* zout, __hip_bfloat16* __restrict__ rout) {
    const int w    = threadIdx.x >> 6;
    const int lane = threadIdx.x & 63;
    const int quad = lane >> 4;
    const int l16  = lane & 15;
    const int row0 = blockIdx.x * 64;

    const __hip_bfloat16* arow[4];
#pragma unroll
    for (int mt = 0; mt < 4; ++mt) {
        int r = row0 + mt * 16 + l16;
        if (r > NN - 1) r = NN - 1;                    // clamp: row stays in-block
        arow[mt] = hin + (size_t)r * K + quad * 8;
    }
    const __hip_bfloat16* brow[4];
#pragma unroll
    for (int nt = 0; nt < 4; ++nt) {
        int n = w * 64 + nt * 16 + l16;
        brow[nt] = wt + (size_t)n * K + quad * 8;
    }

    f32x4 acc[4][4];
#pragma unroll
    for (int mt = 0; mt < 4; ++mt)
#pragma unroll
        for (int nt = 0; nt < 4; ++nt)
            acc[mt][nt] = (f32x4){0.f, 0.f, 0.f, 0.f};

#pragma unroll
    for (int kc = 0; kc < K / 32; ++kc) {
        bf16x8 bf[4];
#pragma unroll
        for (int nt = 0; nt < 4; ++nt)
            bf[nt] = *(const bf16x8*)(brow[nt] + kc * 32);
#pragma unroll
        for (int mt = 0; mt < 4; ++mt) {
            const bf16x8 af = *(const bf16x8*)(arow[mt] + kc * 32);
#pragma unroll
            for (int nt = 0; nt < 4; ++nt)
                acc[mt][nt] = __builtin_amdgcn_mfma_f32_16x16x32_bf16(
                    af, bf[nt], acc[mt][nt], 0, 0, 0);
        }
    }

    __syncthreads();   // in-place safety: all waves' A-loads precede stores

    // C/D layout: col = lane&15, row = quad*4 + reg  [m89 verified]
#pragma unroll
    for (int nt = 0; nt < 4; ++nt) {
        const int colw = nt * 16 + l16;                // 0..63 within wave slice
        const float bi = (w >= 2) ? bias[(w - 2) * 64 + colw] : 0.f;
#pragma unroll
        for (int mt = 0; mt < 4; ++mt) {
#pragma unroll
            for (int reg = 0; reg < 4; ++reg) {
                const int r = row0 + mt * 16 + quad * 4 + reg;
                if (r < NN) {
                    const float v = acc[mt][nt][reg];
                    if (w < 2)
                        zout[(size_t)r * HH + w * 64 + colw] = __float2bfloat16(v);
                    else
                        rout[(size_t)r * HH + (w - 2) * 64 + colw] =
                            __float2bfloat16(v + bi);
                }
            }
        }
    }
}

// ---------------------------------------------------------------------------
// Aggregation + combine: h_out = relu(mean_{in-edges}(z[src]) + r)
// one wave per node, 2 features/lane, f32 accumulation, bf16 buffers.
// ---------------------------------------------------------------------------
__global__ __launch_bounds__(256) void aggregate_kernel(
    const __hip_bfloat16* __restrict__ z, __hip_bfloat16* __restrict__ rio,
    const int* __restrict__ offs, const int* __restrict__ csr,
    const float* __restrict__ inv) {
    const int i    = (blockIdx.x * 256 + threadIdx.x) >> 6;
    const int lane = threadIdx.x & 63;
    if (i >= NN) return;
    const int beg = offs[i], end = offs[i + 1];
    float ax = 0.f, ay = 0.f;
    for (int e = beg; e < end; ++e) {
        const int s = csr[e];
        const __hip_bfloat162 zv = *(const __hip_bfloat162*)&z[(size_t)s * HH + lane * 2];
        ax += __bfloat162float(zv.x);
        ay += __bfloat162float(zv.y);
    }
    const float iv = inv[i];
    const __hip_bfloat162 rv = *(const __hip_bfloat162*)&rio[(size_t)i * HH + lane * 2];
    __hip_bfloat162 o;
    o.x = __float2bfloat16(fmaxf(ax * iv + __bfloat162float(rv.x), 0.f));
    o.y = __float2bfloat16(fmaxf(ay * iv + __bfloat162float(rv.y), 0.f));
    *(__hip_bfloat162*)&rio[(size_t)i * HH + lane * 2] = o;
}

// ---------------------------------------------------------------------------
// Layer 3: z3 = h @ Wl3, r3 = h @ Wr3 + b3 (one wave per node, dot-128)
// ---------------------------------------------------------------------------
__global__ __launch_bounds__(256) void proj3_kernel(
    const __hip_bfloat16* __restrict__ h, const float* __restrict__ Wl,
    const float* __restrict__ Wr, const float* __restrict__ b,
    float* __restrict__ z3, float* __restrict__ r3) {
    const int i    = (blockIdx.x * 256 + threadIdx.x) >> 6;
    const int lane = threadIdx.x & 63;
    if (i >= NN) return;
    const __hip_bfloat162 hv = *(const __hip_bfloat162*)&h[(size_t)i * HH + lane * 2];
    const float2 wl2 = *(const float2*)&Wl[lane * 2];
    const float2 wr2 = *(const float2*)&Wr[lane * 2];
    const float hx = __bfloat162float(hv.x), hy = __bfloat162float(hv.y);
    float al = hx * wl2.x + hy * wl2.y;
    float ar = hx * wr2.x + hy * wr2.y;
#pragma unroll
    for (int m = 32; m; m >>= 1) {
        al += __shfl_xor(al, m, 64);
        ar += __shfl_xor(ar, m, 64);
    }
    if (lane == 0) {
        z3[i] = al;
        r3[i] = ar + b[0];
    }
}

// Final: out[i] = sigmoid(mean(z3[src]) + r3[i]); per-block partial sums
__global__ __launch_bounds__(256) void final_kernel(
    const float* __restrict__ z3, const float* __restrict__ r3,
    const int* __restrict__ offs, const int* __restrict__ csr,
    const float* __restrict__ inv, float* __restrict__ out,
    float* __restrict__ partial) {
    __shared__ float red[4];
    const int i    = (blockIdx.x * 256 + threadIdx.x) >> 6;
    const int lane = threadIdx.x & 63;
    const int w    = threadIdx.x >> 6;
    float v = 0.f;
    if (i < NN) {
        const int beg = offs[i], end = offs[i + 1];
        float a = 0.f;
        for (int e = beg + lane; e < end; e += 64) a += z3[csr[e]];
#pragma unroll
        for (int m = 32; m; m >>= 1) a += __shfl_xor(a, m, 64);
        const float pre = a * inv[i] + r3[i];
        const float s = 1.f / (1.f + __expf(-pre));
        if (lane == 0) { out[i] = s; v = s; }
    }
    if (lane == 0) red[w] = v;
    __syncthreads();
    if (threadIdx.x == 0)
        partial[blockIdx.x] = red[0] + red[1] + red[2] + red[3];
}

__global__ __launch_bounds__(256) void mean_kernel(const float* __restrict__ partial,
                                                   int nb, float* __restrict__ out) {
    __shared__ float lds[256];
    float s = 0.f;
    for (int i = threadIdx.x; i < nb; i += 256) s += partial[i];
    lds[threadIdx.x] = s;
    __syncthreads();
    for (int st = 128; st; st >>= 1) {
        if (threadIdx.x < st) lds[threadIdx.x] += lds[threadIdx.x + st];
        __syncthreads();
    }
    if (threadIdx.x == 0) out[NN] = lds[0] / (float)NN;
}

// ---------------------------------------------------------------------------
extern "C" void kernel_launch(void* const* d_in, const int* in_sizes, int n_in,
                              void* d_out, int out_size, void* d_ws, size_t ws_size,
                              hipStream_t stream) {
    const float* x    = (const float*)d_in[0];
    const float* diff = (const float*)d_in[1];
    const float* rec  = (const float*)d_in[2];
    const float* hid  = (const float*)d_in[3];
    const int* edge   = (const int*)d_in[4];
    const int* esrc = edge;        // row 0
    const int* edst = edge + EE;   // row 1
    const float* Wl0 = (const float*)d_in[5];
    const float* Wr0 = (const float*)d_in[6];
    const float* b0  = (const float*)d_in[7];
    const float* Wl1 = (const float*)d_in[8];
    const float* Wr1 = (const float*)d_in[9];
    const float* b1  = (const float*)d_in[10];
    const float* Wl2 = (const float*)d_in[11];
    const float* Wr2 = (const float*)d_in[12];
    const float* b2  = (const float*)d_in[13];
    const float* Wl3 = (const float*)d_in[14];
    const float* Wr3 = (const float*)d_in[15];
    const float* b3  = (const float*)d_in[16];
    float* out = (float*)d_out;

    // workspace carve-out (256B aligned) — total ~110 MB
    char* w = (char*)d_ws;
    auto alloc = [&](size_t bytes) -> void* {
        void* p = (void*)w;
        w += (bytes + 255) & ~(size_t)255;
        return p;
    };
    __hip_bfloat16* h0   = (__hip_bfloat16*)alloc((size_t)NN * 256 * 2); // 51.2 MB
    __hip_bfloat16* bufA = (__hip_bfloat16*)alloc((size_t)NN * HH * 2);  // 25.6 MB
    __hip_bfloat16* bufB = (__hip_bfloat16*)alloc((size_t)NN * HH * 2);  // 25.6 MB
    __hip_bfloat16* WT0  = (__hip_bfloat16*)alloc((size_t)256 * 256 * 2);
    __hip_bfloat16* WT1  = (__hip_bfloat16*)alloc((size_t)256 * 128 * 2);
    __hip_bfloat16* WT2  = (__hip_bfloat16*)alloc((size_t)256 * 128 * 2);
    int*   csr     = (int*)alloc((size_t)EE * 4);                        // 6.4 MB
    int*   deg     = (int*)alloc((size_t)NN * 4);
    float* inv     = (float*)alloc((size_t)NN * 4);
    int*   offs    = (int*)alloc((size_t)(NN + 1) * 4);
    int*   cursor  = (int*)alloc((size_t)NN * 4);
    float* z3      = (float*)alloc((size_t)NN * 4);
    float* r3      = (float*)alloc((size_t)NN * 4);
    float* partial = (float*)alloc((size_t)25000 * 4);
    int*   bsums   = (int*)alloc((size_t)512 * 4);

    const int EB  = (EE + 255) / 256;        // 6250
    const int NB1 = (NN + 255) / 256;        // 391
    const int GB  = (NN + 63) / 64;          // 1563 (MFMA gemm blocks)
    const int WB  = (NN + 3) / 4;            // 25000 (1 node/wave)
    const int HB  = (NN * 64 + 255) / 256;   // 25000 (h0 convert)

    // CSR build
    zero_kernel<<<NB1, 256, 0, stream>>>(deg, cursor);
    count_kernel<<<EB, 256, 0, stream>>>(edst, deg);
    scan1_kernel<<<NB1, 256, 0, stream>>>(deg, offs, bsums);
    scan2_kernel<<<1, 512, 0, stream>>>(bsums, NB1);
    scan3_kernel<<<NB1, 256, 0, stream>>>(offs, bsums, deg, inv);
    fill_kernel<<<EB, 256, 0, stream>>>(esrc, edst, offs, cursor, csr);

    // bf16 prep
    h0_kernel<<<HB, 256, 0, stream>>>(x, diff, rec, hid, h0);
    prepw_kernel<<<512, 256, 0, stream>>>(Wl0, Wr0, Wl1, Wr1, Wl2, Wr2,
                                          WT0, WT1, WT2);

    // L0: K=256; z -> A, r -> B; agg: h1 -> B (over r)
    gemm_kernel<256><<<GB, 256, 0, stream>>>(h0, WT0, b0, bufA, bufB);
    aggregate_kernel<<<WB, 256, 0, stream>>>(bufA, bufB, offs, csr, inv);

    // L1: h in B; z in-place -> B, r -> A; agg: h2 -> A
    gemm_kernel<128><<<GB, 256, 0, stream>>>(bufB, WT1, b1, bufB, bufA);
    aggregate_kernel<<<WB, 256, 0, stream>>>(bufB, bufA, offs, csr, inv);

    // L2: h in A; z in-place -> A, r -> B; agg: h3 -> B
    gemm_kernel<128><<<GB, 256, 0, stream>>>(bufA, WT2, b2, bufA, bufB);
    aggregate_kernel<<<WB, 256, 0, stream>>>(bufA, bufB, offs, csr, inv);

    // L3: project to scalar, aggregate scalars, sigmoid + mean
    proj3_kernel<<<WB, 256, 0, stream>>>(bufB, Wl3, Wr3, b3, z3, r3);
    final_kernel<<<WB, 256, 0, stream>>>(z3, r3, offs, csr, inv, out, partial);
    mean_kernel<<<1, 256, 0, stream>>>(partial, WB, out);
}

// Round 5
// 752.061 us; speedup vs baseline: 1.7937x; 1.3565x over previous
//
#include <hip/hip_runtime.h>
#include <hip/hip_bf16.h>

// Problem constants (fixed by reference)
#define NN 100000
#define EE 1600000
#define HH 128

typedef short bf16x8 __attribute__((ext_vector_type(8)));
typedef float f32x4  __attribute__((ext_vector_type(4)));

// ---------------------------------------------------------------------------
// init: zero deg + cursor
// ---------------------------------------------------------------------------
__global__ __launch_bounds__(256) void zero_kernel(int* __restrict__ deg,
                                                   int* __restrict__ cursor) {
    int i = blockIdx.x * 256 + threadIdx.x;
    if (i < NN) { deg[i] = 0; cursor[i] = 0; }
}

// ---------------------------------------------------------------------------
// CSR build: count -> scan -> fill
// ---------------------------------------------------------------------------
__global__ __launch_bounds__(256) void count_kernel(const int* __restrict__ dst,
                                                    int* __restrict__ deg) {
    int e = blockIdx.x * 256 + threadIdx.x;
    if (e < EE) atomicAdd(&deg[dst[e]], 1);
}

__global__ __launch_bounds__(256) void scan1_kernel(const int* __restrict__ deg,
                                                    int* __restrict__ offs,
                                                    int* __restrict__ bsums) {
    __shared__ int lds[256];
    int i = blockIdx.x * 256 + threadIdx.x;
    int v = (i < NN) ? deg[i] : 0;
    lds[threadIdx.x] = v;
    __syncthreads();
    for (int st = 1; st < 256; st <<= 1) {
        int t = (threadIdx.x >= st) ? lds[threadIdx.x - st] : 0;
        __syncthreads();
        lds[threadIdx.x] += t;
        __syncthreads();
    }
    if (i < NN) offs[i] = lds[threadIdx.x] - v;       // exclusive within block
    if (threadIdx.x == 255) bsums[blockIdx.x] = lds[255];
}

__global__ __launch_bounds__(512) void scan2_kernel(int* __restrict__ bsums, int nb) {
    __shared__ int lds[512];
    int v = (threadIdx.x < nb) ? bsums[threadIdx.x] : 0;
    lds[threadIdx.x] = v;
    __syncthreads();
    for (int st = 1; st < 512; st <<= 1) {
        int t = (threadIdx.x >= st) ? lds[threadIdx.x - st] : 0;
        __syncthreads();
        lds[threadIdx.x] += t;
        __syncthreads();
    }
    if (threadIdx.x < nb) bsums[threadIdx.x] = lds[threadIdx.x] - v;
}

__global__ __launch_bounds__(256) void scan3_kernel(int* __restrict__ offs,
                                                    const int* __restrict__ bsums,
                                                    const int* __restrict__ deg,
                                                    float* __restrict__ inv) {
    int i = blockIdx.x * 256 + threadIdx.x;
    if (i < NN) {
        offs[i] += bsums[blockIdx.x];
        inv[i] = 1.0f / fmaxf((float)deg[i], 1.0f);
    }
    if (i == 0) offs[NN] = EE;
}

__global__ __launch_bounds__(256) void fill_kernel(const int* __restrict__ srcv,
                                                   const int* __restrict__ dstv,
                                                   const int* __restrict__ offs,
                                                   int* __restrict__ cursor,
                                                   int* __restrict__ csr) {
    int e = blockIdx.x * 256 + threadIdx.x;
    if (e < EE) {
        int d = dstv[e];
        int p = offs[d] + atomicAdd(&cursor[d], 1);
        csr[p] = srcv[e];
    }
}

// ---------------------------------------------------------------------------
// h0 convert: concat 4 f32 [N,64] inputs -> bf16 [N,256]
// ---------------------------------------------------------------------------
__global__ __launch_bounds__(256) void h0_kernel(
    const float* __restrict__ x0, const float* __restrict__ x1,
    const float* __restrict__ x2, const float* __restrict__ x3,
    __hip_bfloat16* __restrict__ h0) {
    int t = blockIdx.x * 256 + threadIdx.x;            // 0 .. N*64-1
    if (t >= NN * 64) return;
    int i = t >> 6;
    int c = (t & 63) * 4;                              // 0..252, step 4
    const float* s = (c < 64) ? x0 : (c < 128) ? x1 : (c < 192) ? x2 : x3;
    float4 v = *(const float4*)&s[(size_t)i * 64 + (c & 63)];
    __hip_bfloat162 p0, p1;
    p0.x = __float2bfloat16(v.x); p0.y = __float2bfloat16(v.y);
    p1.x = __float2bfloat16(v.z); p1.y = __float2bfloat16(v.w);
    *(__hip_bfloat162*)&h0[(size_t)i * 256 + c]     = p0;
    *(__hip_bfloat162*)&h0[(size_t)i * 256 + c + 2] = p1;
}

// ---------------------------------------------------------------------------
// Weight prep: WT[n][k] = (n<128 ? Wl[k][n] : Wr[k][n-128]) as bf16.
// ---------------------------------------------------------------------------
__global__ __launch_bounds__(256) void prepw_kernel(
    const float* __restrict__ Wl0, const float* __restrict__ Wr0,
    const float* __restrict__ Wl1, const float* __restrict__ Wr1,
    const float* __restrict__ Wl2, const float* __restrict__ Wr2,
    __hip_bfloat16* __restrict__ WT0, __hip_bfloat16* __restrict__ WT1,
    __hip_bfloat16* __restrict__ WT2) {
    int t = blockIdx.x * 256 + threadIdx.x;            // 0 .. 131071
    if (t < 65536) {                                   // layer 0: K=256
        int k = t & 255, n = t >> 8;
        float v = (n < 128) ? Wl0[(size_t)k * 128 + n] : Wr0[(size_t)k * 128 + (n - 128)];
        WT0[(size_t)n * 256 + k] = __float2bfloat16(v);
    } else {
        t -= 65536;
        int layer = t >> 15;                           // 0 -> L1, 1 -> L2
        int u = t & 32767;
        int k = u & 127, n = u >> 7;
        const float* Wl = layer ? Wl2 : Wl1;
        const float* Wr = layer ? Wr2 : Wr1;
        __hip_bfloat16* WT = layer ? WT2 : WT1;
        float v = (n < 128) ? Wl[(size_t)k * 128 + n] : Wr[(size_t)k * 128 + (n - 128)];
        WT[(size_t)n * 128 + k] = __float2bfloat16(v);
    }
}

// ---------------------------------------------------------------------------
// MFMA GEMM: [z | r] = h @ [Wl | Wr] (+b on r). bf16 in, f32 acc, bf16 out.
// Block = 256 threads = 4 waves; tile = 64 rows x 256 cols. No LDS.
// zout may alias hin (in-place): __syncthreads() orders loads before stores.
// ---------------------------------------------------------------------------
template <int K>
__global__ __launch_bounds__(256) void gemm_kernel(
    const __hip_bfloat16* hin, const __hip_bfloat16* __restrict__ wt,
    const float* __restrict__ bias,
    __hip_bfloat16* zout, __hip_bfloat16* __restrict__ rout) {
    const int w    = threadIdx.x >> 6;
    const int lane = threadIdx.x & 63;
    const int quad = lane >> 4;
    const int l16  = lane & 15;
    const int row0 = blockIdx.x * 64;

    const __hip_bfloat16* arow[4];
#pragma unroll
    for (int mt = 0; mt < 4; ++mt) {
        int r = row0 + mt * 16 + l16;
        if (r > NN - 1) r = NN - 1;                    // clamp: row stays in-block
        arow[mt] = hin + (size_t)r * K + quad * 8;
    }
    const __hip_bfloat16* brow[4];
#pragma unroll
    for (int nt = 0; nt < 4; ++nt) {
        int n = w * 64 + nt * 16 + l16;
        brow[nt] = wt + (size_t)n * K + quad * 8;
    }

    f32x4 acc[4][4];
#pragma unroll
    for (int mt = 0; mt < 4; ++mt)
#pragma unroll
        for (int nt = 0; nt < 4; ++nt)
            acc[mt][nt] = (f32x4){0.f, 0.f, 0.f, 0.f};

#pragma unroll
    for (int kc = 0; kc < K / 32; ++kc) {
        bf16x8 bf[4];
#pragma unroll
        for (int nt = 0; nt < 4; ++nt)
            bf[nt] = *(const bf16x8*)(brow[nt] + kc * 32);
#pragma unroll
        for (int mt = 0; mt < 4; ++mt) {
            const bf16x8 af = *(const bf16x8*)(arow[mt] + kc * 32);
#pragma unroll
            for (int nt = 0; nt < 4; ++nt)
                acc[mt][nt] = __builtin_amdgcn_mfma_f32_16x16x32_bf16(
                    af, bf[nt], acc[mt][nt], 0, 0, 0);
        }
    }

    __syncthreads();   // in-place safety: all waves' A-loads precede stores

    // C/D layout: col = lane&15, row = quad*4 + reg  [m89 verified]
#pragma unroll
    for (int nt = 0; nt < 4; ++nt) {
        const int colw = nt * 16 + l16;
        const float bi = (w >= 2) ? bias[(w - 2) * 64 + colw] : 0.f;
#pragma unroll
        for (int mt = 0; mt < 4; ++mt) {
#pragma unroll
            for (int reg = 0; reg < 4; ++reg) {
                const int r = row0 + mt * 16 + quad * 4 + reg;
                if (r < NN) {
                    const float v = acc[mt][nt][reg];
                    if (w < 2)
                        zout[(size_t)r * HH + w * 64 + colw] = __float2bfloat16(v);
                    else
                        rout[(size_t)r * HH + (w - 2) * 64 + colw] =
                            __float2bfloat16(v + bi);
                }
            }
        }
    }
}

// ---------------------------------------------------------------------------
// Aggregation + combine: h_out = relu(mean_{in-edges}(z[src]) + r)
// One wave per node; 4 groups x 16 lanes; each lane loads bf16x8 (16B), a
// group covers one 256B z-row, so 4 edges/iteration; 2x manual unroll gives
// 8 gathers in flight per wave. Cross-group butterfly (xor 16,32) at the end.
// ---------------------------------------------------------------------------
__global__ __launch_bounds__(256) void aggregate_kernel(
    const __hip_bfloat16* __restrict__ z, __hip_bfloat16* __restrict__ rio,
    const int* __restrict__ offs, const int* __restrict__ csr,
    const float* __restrict__ inv) {
    const int i    = (blockIdx.x * 256 + threadIdx.x) >> 6;
    const int lane = threadIdx.x & 63;
    const int g    = lane >> 4;          // edge slot 0..3
    const int l16  = lane & 15;          // 16B chunk within the z row
    if (i >= NN) return;
    const int beg = offs[i], end = offs[i + 1];

    float acc[8];
#pragma unroll
    for (int j = 0; j < 8; ++j) acc[j] = 0.f;

    int e = beg + g;
    // 2x unrolled: two independent 256B gathers per group in flight
    for (; e + 4 < end; e += 8) {
        const int s0 = csr[e];
        const int s1 = csr[e + 4];
        const bf16x8 z0 = *(const bf16x8*)&z[(size_t)s0 * HH + l16 * 8];
        const bf16x8 z1 = *(const bf16x8*)&z[(size_t)s1 * HH + l16 * 8];
        const __hip_bfloat162* p0 = (const __hip_bfloat162*)&z0;
        const __hip_bfloat162* p1 = (const __hip_bfloat162*)&z1;
#pragma unroll
        for (int j = 0; j < 4; ++j) {
            acc[2 * j]     += __bfloat162float(p0[j].x) + __bfloat162float(p1[j].x);
            acc[2 * j + 1] += __bfloat162float(p0[j].y) + __bfloat162float(p1[j].y);
        }
    }
    if (e < end) {
        const int s0 = csr[e];
        const bf16x8 z0 = *(const bf16x8*)&z[(size_t)s0 * HH + l16 * 8];
        const __hip_bfloat162* p0 = (const __hip_bfloat162*)&z0;
#pragma unroll
        for (int j = 0; j < 4; ++j) {
            acc[2 * j]     += __bfloat162float(p0[j].x);
            acc[2 * j + 1] += __bfloat162float(p0[j].y);
        }
    }

    // butterfly across the 4 groups (lane bits 4 and 5)
#pragma unroll
    for (int j = 0; j < 8; ++j) {
        acc[j] += __shfl_xor(acc[j], 16, 64);
        acc[j] += __shfl_xor(acc[j], 32, 64);
    }

    // every lane finalizes 2 features: f = l16*8 + g*2
    const float iv = inv[i];
    const int   f  = l16 * 8 + g * 2;
    const __hip_bfloat162 rv = *(const __hip_bfloat162*)&rio[(size_t)i * HH + f];
    __hip_bfloat162 o;
    o.x = __float2bfloat16(fmaxf(acc[g * 2]     * iv + __bfloat162float(rv.x), 0.f));
    o.y = __float2bfloat16(fmaxf(acc[g * 2 + 1] * iv + __bfloat162float(rv.y), 0.f));
    *(__hip_bfloat162*)&rio[(size_t)i * HH + f] = o;
}

// ---------------------------------------------------------------------------
// Layer 3: z3 = h @ Wl3, r3 = h @ Wr3 + b3 (one wave per node, dot-128)
// ---------------------------------------------------------------------------
__global__ __launch_bounds__(256) void proj3_kernel(
    const __hip_bfloat16* __restrict__ h, const float* __restrict__ Wl,
    const float* __restrict__ Wr, const float* __restrict__ b,
    float* __restrict__ z3, float* __restrict__ r3) {
    const int i    = (blockIdx.x * 256 + threadIdx.x) >> 6;
    const int lane = threadIdx.x & 63;
    if (i >= NN) return;
    const __hip_bfloat162 hv = *(const __hip_bfloat162*)&h[(size_t)i * HH + lane * 2];
    const float2 wl2 = *(const float2*)&Wl[lane * 2];
    const float2 wr2 = *(const float2*)&Wr[lane * 2];
    const float hx = __bfloat162float(hv.x), hy = __bfloat162float(hv.y);
    float al = hx * wl2.x + hy * wl2.y;
    float ar = hx * wr2.x + hy * wr2.y;
#pragma unroll
    for (int m = 32; m; m >>= 1) {
        al += __shfl_xor(al, m, 64);
        ar += __shfl_xor(ar, m, 64);
    }
    if (lane == 0) {
        z3[i] = al;
        r3[i] = ar + b[0];
    }
}

// Final: out[i] = sigmoid(mean(z3[src]) + r3[i]); per-block partial sums
__global__ __launch_bounds__(256) void final_kernel(
    const float* __restrict__ z3, const float* __restrict__ r3,
    const int* __restrict__ offs, const int* __restrict__ csr,
    const float* __restrict__ inv, float* __restrict__ out,
    float* __restrict__ partial) {
    __shared__ float red[4];
    const int i    = (blockIdx.x * 256 + threadIdx.x) >> 6;
    const int lane = threadIdx.x & 63;
    const int w    = threadIdx.x >> 6;
    float v = 0.f;
    if (i < NN) {
        const int beg = offs[i], end = offs[i + 1];
        float a = 0.f;
        for (int e = beg + lane; e < end; e += 64) a += z3[csr[e]];
#pragma unroll
        for (int m = 32; m; m >>= 1) a += __shfl_xor(a, m, 64);
        const float pre = a * inv[i] + r3[i];
        const float s = 1.f / (1.f + __expf(-pre));
        if (lane == 0) { out[i] = s; v = s; }
    }
    if (lane == 0) red[w] = v;
    __syncthreads();
    if (threadIdx.x == 0)
        partial[blockIdx.x] = red[0] + red[1] + red[2] + red[3];
}

__global__ __launch_bounds__(256) void mean_kernel(const float* __restrict__ partial,
                                                   int nb, float* __restrict__ out) {
    __shared__ float lds[256];
    float s = 0.f;
    for (int i = threadIdx.x; i < nb; i += 256) s += partial[i];
    lds[threadIdx.x] = s;
    __syncthreads();
    for (int st = 128; st; st >>= 1) {
        if (threadIdx.x < st) lds[threadIdx.x] += lds[threadIdx.x + st];
        __syncthreads();
    }
    if (threadIdx.x == 0) out[NN] = lds[0] / (float)NN;
}

// ---------------------------------------------------------------------------
extern "C" void kernel_launch(void* const* d_in, const int* in_sizes, int n_in,
                              void* d_out, int out_size, void* d_ws, size_t ws_size,
                              hipStream_t stream) {
    const float* x    = (const float*)d_in[0];
    const float* diff = (const float*)d_in[1];
    const float* rec  = (const float*)d_in[2];
    const float* hid  = (const float*)d_in[3];
    const int* edge   = (const int*)d_in[4];
    const int* esrc = edge;        // row 0
    const int* edst = edge + EE;   // row 1
    const float* Wl0 = (const float*)d_in[5];
    const float* Wr0 = (const float*)d_in[6];
    const float* b0  = (const float*)d_in[7];
    const float* Wl1 = (const float*)d_in[8];
    const float* Wr1 = (const float*)d_in[9];
    const float* b1  = (const float*)d_in[10];
    const float* Wl2 = (const float*)d_in[11];
    const float* Wr2 = (const float*)d_in[12];
    const float* b2  = (const float*)d_in[13];
    const float* Wl3 = (const float*)d_in[14];
    const float* Wr3 = (const float*)d_in[15];
    const float* b3  = (const float*)d_in[16];
    float* out = (float*)d_out;

    // workspace carve-out (256B aligned) — total ~110 MB
    char* w = (char*)d_ws;
    auto alloc = [&](size_t bytes) -> void* {
        void* p = (void*)w;
        w += (bytes + 255) & ~(size_t)255;
        return p;
    };
    __hip_bfloat16* h0   = (__hip_bfloat16*)alloc((size_t)NN * 256 * 2); // 51.2 MB
    __hip_bfloat16* bufA = (__hip_bfloat16*)alloc((size_t)NN * HH * 2);  // 25.6 MB
    __hip_bfloat16* bufB = (__hip_bfloat16*)alloc((size_t)NN * HH * 2);  // 25.6 MB
    __hip_bfloat16* WT0  = (__hip_bfloat16*)alloc((size_t)256 * 256 * 2);
    __hip_bfloat16* WT1  = (__hip_bfloat16*)alloc((size_t)256 * 128 * 2);
    __hip_bfloat16* WT2  = (__hip_bfloat16*)alloc((size_t)256 * 128 * 2);
    int*   csr     = (int*)alloc((size_t)EE * 4);                        // 6.4 MB
    int*   deg     = (int*)alloc((size_t)NN * 4);
    float* inv     = (float*)alloc((size_t)NN * 4);
    int*   offs    = (int*)alloc((size_t)(NN + 1) * 4);
    int*   cursor  = (int*)alloc((size_t)NN * 4);
    float* z3      = (float*)alloc((size_t)NN * 4);
    float* r3      = (float*)alloc((size_t)NN * 4);
    float* partial = (float*)alloc((size_t)25000 * 4);
    int*   bsums   = (int*)alloc((size_t)512 * 4);

    const int EB  = (EE + 255) / 256;        // 6250
    const int NB1 = (NN + 255) / 256;        // 391
    const int GB  = (NN + 63) / 64;          // 1563 (MFMA gemm blocks)
    const int WB  = (NN + 3) / 4;            // 25000 (1 node/wave)
    const int HB  = (NN * 64 + 255) / 256;   // 25000 (h0 convert)

    // CSR build
    zero_kernel<<<NB1, 256, 0, stream>>>(deg, cursor);
    count_kernel<<<EB, 256, 0, stream>>>(edst, deg);
    scan1_kernel<<<NB1, 256, 0, stream>>>(deg, offs, bsums);
    scan2_kernel<<<1, 512, 0, stream>>>(bsums, NB1);
    scan3_kernel<<<NB1, 256, 0, stream>>>(offs, bsums, deg, inv);
    fill_kernel<<<EB, 256, 0, stream>>>(esrc, edst, offs, cursor, csr);

    // bf16 prep
    h0_kernel<<<HB, 256, 0, stream>>>(x, diff, rec, hid, h0);
    prepw_kernel<<<512, 256, 0, stream>>>(Wl0, Wr0, Wl1, Wr1, Wl2, Wr2,
                                          WT0, WT1, WT2);

    // L0: K=256; z -> A, r -> B; agg: h1 -> B (over r)
    gemm_kernel<256><<<GB, 256, 0, stream>>>(h0, WT0, b0, bufA, bufB);
    aggregate_kernel<<<WB, 256, 0, stream>>>(bufA, bufB, offs, csr, inv);

    // L1: h in B; z in-place -> B, r -> A; agg: h2 -> A
    gemm_kernel<128><<<GB, 256, 0, stream>>>(bufB, WT1, b1, bufB, bufA);
    aggregate_kernel<<<WB, 256, 0, stream>>>(bufB, bufA, offs, csr, inv);

    // L2: h in A; z in-place -> A, r -> B; agg: h3 -> B
    gemm_kernel<128><<<GB, 256, 0, stream>>>(bufA, WT2, b2, bufA, bufB);
    aggregate_kernel<<<WB, 256, 0, stream>>>(bufA, bufB, offs, csr, inv);

    // L3: project to scalar, aggregate scalars, sigmoid + mean
    proj3_kernel<<<WB, 256, 0, stream>>>(bufB, Wl3, Wr3, b3, z3, r3);
    final_kernel<<<WB, 256, 0, stream>>>(z3, r3, offs, csr, inv, out, partial);
    mean_kernel<<<1, 256, 0, stream>>>(partial, WB, out);
}